// Round 9
// baseline (240.552 us; speedup 1.0000x reference)
//
#include <hip/hip_runtime.h>

typedef float f32x4 __attribute__((ext_vector_type(4)));

// DB4: dec_lo[j] = h[7-j] (h = rec_lo). Only the low-pass path is needed:
// residual = IDWT3(a3,0,0,0); seasonal = x - residual  (linearity + perfect
// reconstruction of the periodized orthogonal transform).
static constexpr float LO[8] = {
    -0.010597401784997278f,  0.032883011666982945f,  0.030841381835986965f,
    -0.18703481171888114f,  -0.02798376941698385f,   0.6308807679295904f,
     0.7148465705525415f,    0.23037781330885523f
};

// Forward low-pass, per-lane: C inputs -> C/2 outputs.
// a[i'] = sum_j w(2i'+1-j)*LO[j]; w(t) = t>=0 ? in[t] : hp[t+6]
// hp = prev lane's in[C-6..C-1] (ring periodic).
template<int C>
__device__ __forceinline__ void fwd_lo(const float* __restrict__ in,
                                       const float* __restrict__ hp,
                                       float* __restrict__ a)
{
    #pragma unroll
    for (int i = 0; i < C / 2; ++i) {
        float s = 0.f;
        #pragma unroll
        for (int j = 0; j < 8; ++j) {
            const int t = 2 * i + 1 - j;            // [-6 .. C-1]
            const float v = (t >= 0) ? in[t >= 0 ? t : 0]
                                     : hp[t < 0 ? t + 6 : 0];
            s = fmaf(v, LO[j], s);
        }
        a[i] = s;
    }
}

// Inverse low-pass (cD = 0), per-lane: K coeffs -> 2K outputs.
// y[2m'] = sum_q va(m'+q)*LO[2q+1]; y[2m'+1] = sum_q va(m'+q)*LO[2q]
// va(t) = t<K ? a[t] : hn[t-K]; hn = next lane's a[0..2].
template<int K>
__device__ __forceinline__ void inv_lo(const float* __restrict__ a,
                                       const float* __restrict__ hn,
                                       float* __restrict__ y)
{
    #pragma unroll
    for (int m = 0; m < K; ++m) {
        float e0 = 0.f, e1 = 0.f;
        #pragma unroll
        for (int q = 0; q < 4; ++q) {
            const int t = m + q;                    // [0 .. K+2]
            const float v = (t < K) ? a[t < K ? t : 0]
                                    : hn[t >= K ? t - K : 0];
            e0 = fmaf(v, LO[2 * q + 1], e0);
            e1 = fmaf(v, LO[2 * q],     e1);
        }
        y[2 * m]     = e0;
        y[2 * m + 1] = e1;
    }
}

// One wave per row (4096 = 64 lanes x 64 elems). All state in registers;
// periodic halos via ring __shfl. No LDS, no barriers.
__global__ __launch_bounds__(256, 2)
void WaveletSeasonalDecomposer_43181601194295_kernel(const float* __restrict__ in,
                                                     float* __restrict__ seasonal,
                                                     float* __restrict__ residual)
{
    const int lane = threadIdx.x & 63;
    const int wave = threadIdx.x >> 6;
    const int row  = (blockIdx.x << 2) + wave;
    const int prev = (lane + 63) & 63;
    const int next = (lane + 1) & 63;

    const size_t rbase = (size_t)row * 4096 + (size_t)lane * 64;
    const float* xr = in + rbase;

    // ---- load lane chunk (per-lane contiguous 256B)
    float x[64];
    #pragma unroll
    for (int c = 0; c < 16; ++c) {
        const f32x4 v = *(const f32x4*)(xr + 4 * c);
        x[4 * c + 0] = v.x; x[4 * c + 1] = v.y;
        x[4 * c + 2] = v.z; x[4 * c + 3] = v.w;
    }

    // ---- forward low-pass cascade: x -> a1 -> a2 -> a3
    float hx[6];
    #pragma unroll
    for (int k = 0; k < 6; ++k) hx[k] = __shfl(x[58 + k], prev, 64);
    float a1[32];
    fwd_lo<64>(x, hx, a1);                 // x dead after this

    float h1[6];
    #pragma unroll
    for (int k = 0; k < 6; ++k) h1[k] = __shfl(a1[26 + k], prev, 64);
    float a2[16];
    fwd_lo<32>(a1, h1, a2);

    float h2[6];
    #pragma unroll
    for (int k = 0; k < 6; ++k) h2[k] = __shfl(a2[10 + k], prev, 64);
    float a3[8];
    fwd_lo<16>(a2, h2, a3);

    // ---- inverse low-pass cascade: a3 -> y2 -> y1 -> r (streamed)
    float n3[3];
    #pragma unroll
    for (int k = 0; k < 3; ++k) n3[k] = __shfl(a3[k], next, 64);
    float y2[16];
    inv_lo<8>(a3, n3, y2);

    float n2[3];
    #pragma unroll
    for (int k = 0; k < 3; ++k) n2[k] = __shfl(y2[k], next, 64);
    float y1[32];
    inv_lo<16>(y2, n2, y1);

    float n1[3];
    #pragma unroll
    for (int k = 0; k < 3; ++k) n1[k] = __shfl(y1[k], next, 64);

    float* sr = seasonal + rbase;
    float* rr = residual + rbase;

    // Final inverse level chunked (16 outputs at a time), fused with
    // x-reload (L2/L3-hot) and both stores. r = residual; seasonal = x - r.
    #pragma unroll
    for (int c = 0; c < 4; ++c) {
        float r[16];
        #pragma unroll
        for (int mm = 0; mm < 8; ++mm) {
            const int m = 8 * c + mm;
            float e0 = 0.f, e1 = 0.f;
            #pragma unroll
            for (int q = 0; q < 4; ++q) {
                const int t = m + q;               // [0 .. 34]
                const float v = (t < 32) ? y1[t < 32 ? t : 0]
                                         : n1[t >= 32 ? t - 32 : 0];
                e0 = fmaf(v, LO[2 * q + 1], e0);
                e1 = fmaf(v, LO[2 * q],     e1);
            }
            r[2 * mm]     = e0;
            r[2 * mm + 1] = e1;
        }
        #pragma unroll
        for (int c4 = 0; c4 < 4; ++c4) {
            const int off = 16 * c + 4 * c4;
            const f32x4 xv = *(const f32x4*)(xr + off);
            f32x4 rv;
            rv.x = r[4 * c4 + 0]; rv.y = r[4 * c4 + 1];
            rv.z = r[4 * c4 + 2]; rv.w = r[4 * c4 + 3];
            const f32x4 sv = xv - rv;
            __builtin_nontemporal_store(sv, (f32x4*)(sr + off));
            __builtin_nontemporal_store(rv, (f32x4*)(rr + off));
        }
    }
}

extern "C" void kernel_launch(void* const* d_in, const int* in_sizes, int n_in,
                              void* d_out, int out_size, void* d_ws, size_t ws_size,
                              hipStream_t stream) {
    const float* in = (const float*)d_in[0];
    const int rows = in_sizes[0] / 4096;   // 2048
    float* seasonal = (float*)d_out;
    float* residual = seasonal + (size_t)rows * 4096;
    WaveletSeasonalDecomposer_43181601194295_kernel<<<dim3(rows / 4), dim3(256), 0, stream>>>(
        in, seasonal, residual);
}

// Round 11
// 179.620 us; speedup vs baseline: 1.3392x; 1.3392x over previous
//
#include <hip/hip_runtime.h>

typedef float f32x4 __attribute__((ext_vector_type(4)));

// DB4 rec_lo reversed = dec_lo. Low-pass-only algebra:
// lp = IDWT3(a3,0,0,0); residual = lp; seasonal = x - lp.
// (linearity + perfect reconstruction of periodized orthogonal DWT;
//  validated on HW in R9: passed absmax check)
static constexpr float LO[8] = {
    -0.010597401784997278f,  0.032883011666982945f,  0.030841381835986965f,
    -0.18703481171888114f,  -0.02798376941698385f,   0.6308807679295904f,
     0.7148465705525415f,    0.23037781330885523f
};

// One 256-thread block (4 waves) per row of 4096. Wave w owns [1024w,1024w+1024);
// lane l owns 16 contiguous elements. Forward halo: 6-before via __shfl(l-1)
// (+LDS for wave boundary). Inverse halo: 3-after via __shfl(l+1..2) (+LDS).
// halo[level][wave][slot]: 6*4*8 floats = 768 B LDS. One barrier per level.
__global__ __launch_bounds__(256, 4)
void WaveletSeasonalDecomposer_43181601194295_kernel(const float* __restrict__ in,
                                                     float* __restrict__ seasonal,
                                                     float* __restrict__ residual)
{
    __shared__ float halo[6][4][8];
    const int tid = threadIdx.x;
    const int l   = tid & 63;
    const int w   = tid >> 6;
    const int wp  = (w + 3) & 3;   // prev wave (periodic within row)
    const int wn  = (w + 1) & 3;   // next wave

    const size_t base = (size_t)blockIdx.x * 4096 + (size_t)w * 1024 + (size_t)l * 16;
    const float* xp = in + base;

    // ---- load 16 floats/lane
    float x[16];
    #pragma unroll
    for (int c = 0; c < 4; ++c) {
        const f32x4 v = *(const f32x4*)(xp + 4 * c);
        x[4*c+0] = v.x; x[4*c+1] = v.y; x[4*c+2] = v.z; x[4*c+3] = v.w;
    }

    // ================= FWD L1: x(16/lane) -> a1(8/lane) =================
    if (l == 63) {
        #pragma unroll
        for (int e = 10; e < 16; ++e) halo[0][w][e - 10] = x[e];
    }
    __syncthreads();
    float h[6];
    #pragma unroll
    for (int k = 0; k < 6; ++k) h[k] = __shfl(x[10 + k], l - 1, 64);
    if (l == 0) {
        #pragma unroll
        for (int k = 0; k < 6; ++k) h[k] = halo[0][wp][k];
    }
    float a1[8];
    #pragma unroll
    for (int i = 0; i < 8; ++i) {
        float s = 0.f;
        #pragma unroll
        for (int j = 0; j < 8; ++j) {
            const int t = 2 * i + j;                 // ext idx 0..21
            const float v = (t < 6) ? h[t < 6 ? t : 0] : x[t >= 6 ? t - 6 : 0];
            s = fmaf(v, LO[7 - j], s);
        }
        a1[i] = s;
    }

    // ================= FWD L2: a1(8/lane) -> a2(4/lane) =================
    if (l == 63) {
        #pragma unroll
        for (int e = 2; e < 8; ++e) halo[1][w][e - 2] = a1[e];
    }
    __syncthreads();
    #pragma unroll
    for (int k = 0; k < 6; ++k) h[k] = __shfl(a1[2 + k], l - 1, 64);
    if (l == 0) {
        #pragma unroll
        for (int k = 0; k < 6; ++k) h[k] = halo[1][wp][k];
    }
    float a2[4];
    #pragma unroll
    for (int i = 0; i < 4; ++i) {
        float s = 0.f;
        #pragma unroll
        for (int j = 0; j < 8; ++j) {
            const int t = 2 * i + j;                 // 0..13
            const float v = (t < 6) ? h[t < 6 ? t : 0] : a1[t >= 6 ? t - 6 : 0];
            s = fmaf(v, LO[7 - j], s);
        }
        a2[i] = s;
    }

    // ================= FWD L3: a2(4/lane) -> a3(2/lane) =================
    if (l == 62) { halo[2][w][0] = a2[2]; halo[2][w][1] = a2[3]; }
    if (l == 63) {
        #pragma unroll
        for (int e = 0; e < 4; ++e) halo[2][w][2 + e] = a2[e];
    }
    __syncthreads();
    h[0] = __shfl(a2[2], l - 2, 64);
    h[1] = __shfl(a2[3], l - 2, 64);
    #pragma unroll
    for (int k = 2; k < 6; ++k) h[k] = __shfl(a2[k - 2], l - 1, 64);
    if (l < 2) {
        #pragma unroll
        for (int k = 0; k < 6; ++k)
            if (4 * l + k < 6) h[k] = halo[2][wp][4 * l + k];
    }
    float a3[2];
    #pragma unroll
    for (int i = 0; i < 2; ++i) {
        float s = 0.f;
        #pragma unroll
        for (int j = 0; j < 8; ++j) {
            const int t = 2 * i + j;                 // 0..9
            const float v = (t < 6) ? h[t < 6 ? t : 0] : a2[t >= 6 ? t - 6 : 0];
            s = fmaf(v, LO[7 - j], s);
        }
        a3[i] = s;
    }

    // ================= INV L3: a3(2/lane) -> y2(4/lane) =================
    if (l == 0) { halo[3][w][0] = a3[0]; halo[3][w][1] = a3[1]; }
    if (l == 1) { halo[3][w][2] = a3[0]; }
    __syncthreads();
    float hn[3];
    hn[0] = __shfl(a3[0], l + 1, 64);
    hn[1] = __shfl(a3[1], l + 1, 64);
    hn[2] = __shfl(a3[0], l + 2, 64);
    #pragma unroll
    for (int k = 0; k < 3; ++k) {
        const int g = 2 * (l + 1) + k;
        if (g >= 128) hn[k] = halo[3][wn][g - 128];
    }
    float y2[4];
    #pragma unroll
    for (int m = 0; m < 2; ++m) {
        float e0 = 0.f, e1 = 0.f;
        #pragma unroll
        for (int q = 0; q < 4; ++q) {
            const int t = m + q;                     // 0..4
            const float v = (t < 2) ? a3[t < 2 ? t : 0] : hn[t >= 2 ? t - 2 : 0];
            e0 = fmaf(v, LO[2 * q + 1], e0);
            e1 = fmaf(v, LO[2 * q],     e1);
        }
        y2[2 * m]     = e0;
        y2[2 * m + 1] = e1;
    }

    // ================= INV L2: y2(4/lane) -> y1(8/lane) =================
    if (l == 0) { halo[4][w][0] = y2[0]; halo[4][w][1] = y2[1]; halo[4][w][2] = y2[2]; }
    __syncthreads();
    #pragma unroll
    for (int k = 0; k < 3; ++k) hn[k] = __shfl(y2[k], l + 1, 64);
    if (l == 63) {
        #pragma unroll
        for (int k = 0; k < 3; ++k) hn[k] = halo[4][wn][k];
    }
    float y1[8];
    #pragma unroll
    for (int m = 0; m < 4; ++m) {
        float e0 = 0.f, e1 = 0.f;
        #pragma unroll
        for (int q = 0; q < 4; ++q) {
            const int t = m + q;                     // 0..6
            const float v = (t < 4) ? y2[t < 4 ? t : 0] : hn[t >= 4 ? t - 4 : 0];
            e0 = fmaf(v, LO[2 * q + 1], e0);
            e1 = fmaf(v, LO[2 * q],     e1);
        }
        y1[2 * m]     = e0;
        y1[2 * m + 1] = e1;
    }

    // ===== INV L1: y1(8/lane) -> lp(16/lane), fused residual/seasonal =====
    if (l == 0) { halo[5][w][0] = y1[0]; halo[5][w][1] = y1[1]; halo[5][w][2] = y1[2]; }
    __syncthreads();
    #pragma unroll
    for (int k = 0; k < 3; ++k) hn[k] = __shfl(y1[k], l + 1, 64);
    if (l == 63) {
        #pragma unroll
        for (int k = 0; k < 3; ++k) hn[k] = halo[5][wn][k];
    }
    float r[16];
    #pragma unroll
    for (int m = 0; m < 8; ++m) {
        float e0 = 0.f, e1 = 0.f;
        #pragma unroll
        for (int q = 0; q < 4; ++q) {
            const int t = m + q;                     // 0..10
            const float v = (t < 8) ? y1[t < 8 ? t : 0] : hn[t >= 8 ? t - 8 : 0];
            e0 = fmaf(v, LO[2 * q + 1], e0);
            e1 = fmaf(v, LO[2 * q],     e1);
        }
        r[2 * m]     = e0;
        r[2 * m + 1] = e1;
    }

    float* sr = seasonal + base;
    float* rr = residual + base;
    #pragma unroll
    for (int c = 0; c < 4; ++c) {
        f32x4 rv;
        rv.x = r[4*c+0]; rv.y = r[4*c+1]; rv.z = r[4*c+2]; rv.w = r[4*c+3];
        f32x4 sv;
        sv.x = x[4*c+0] - rv.x; sv.y = x[4*c+1] - rv.y;
        sv.z = x[4*c+2] - rv.z; sv.w = x[4*c+3] - rv.w;
        __builtin_nontemporal_store(sv, (f32x4*)(sr + 4 * c));
        __builtin_nontemporal_store(rv, (f32x4*)(rr + 4 * c));
    }
}

extern "C" void kernel_launch(void* const* d_in, const int* in_sizes, int n_in,
                              void* d_out, int out_size, void* d_ws, size_t ws_size,
                              hipStream_t stream) {
    const float* in = (const float*)d_in[0];
    const int rows = in_sizes[0] / 4096;   // 2048
    float* seasonal = (float*)d_out;
    float* residual = seasonal + (size_t)rows * 4096;
    WaveletSeasonalDecomposer_43181601194295_kernel<<<dim3(rows), dim3(256), 0, stream>>>(
        in, seasonal, residual);
}